// Round 10
// baseline (155.713 us; speedup 1.0000x reference)
//
#include <hip/hip_runtime.h>
#include <math.h>

// Problem constants (reference: N=64, H=512, W=512, RATIO=2, ITERATIONS=1)
#define NIMG 64
#define HH 512
#define WW 512
#define NPIX (NIMG * HH * WW)          // 16,777,216
#define MASK_BYTES (NPIX / 8)          // 2 MB: 1 bit per pixel
#define NBLK_A 8192                    // 2M threads, 8 px each
#define NBLK_B 2048                    // 512K threads, 32 px each (4x8 patch)
#define INV_TOTAL (1.0f / 16777216.0f) // exact pow2

typedef unsigned int u32;
typedef unsigned char u8;

// ---------------- Kernel A: y (int32, 64 MB) -> bitmask (2 MB) -------------
// Byte i = pixels 8i..8i+7, bit k = (y[8i+k] > 0). Dense stride-32B loads.
// Also zeroes the output accumulator (B atomically adds into it).
__global__ __launch_bounds__(256, 8) void border_mask_gen(
    const int* __restrict__ y, u8* __restrict__ mask, float* __restrict__ out)
{
    const int idx = blockIdx.x * 256 + threadIdx.x;
    const int4 a = ((const int4*)y)[idx * 2];
    const int4 b = ((const int4*)y)[idx * 2 + 1];
    const u32 m = (u32)(a.x > 0)        | ((u32)(a.y > 0) << 1)
                | ((u32)(a.z > 0) << 2) | ((u32)(a.w > 0) << 3)
                | ((u32)(b.x > 0) << 4) | ((u32)(b.y > 0) << 5)
                | ((u32)(b.z > 0) << 6) | ((u32)(b.w > 0) << 7);
    mask[idx] = (u8)m;
    if (idx == 0) out[0] = 0.0f;
}

// ---------------- Kernel B: x (64 MB) + bitmask (3 MB read) -> loss --------
// One thread = 4 rows x 8 cols patch; one wave = 4 full image rows.
// 6 mask-byte loads cover all 4 rows' vertical windows (replicate row clamp
// — exact for idempotent OR/AND). All 4 rows' morphology packs into one u32
// (byte j = row j): one shfl pair + masked byte-wise shifts for horizontal.
// border = HO ^ HA (OR superset of AND). Ends in one atomicAdd per block.
__global__ __launch_bounds__(256, 8) void border_loss_bits(
    const float* __restrict__ x, const u8* __restrict__ mask,
    float* __restrict__ out)
{
    __shared__ float wsum[4];

    const int tid  = threadIdx.x;
    const int lane = tid & 63;
    const int wid  = blockIdx.x * 4 + (tid >> 6);  // global wave 0..8191
    const int r0   = wid << 2;                     // first of 4 global rows
    const int n    = r0 >> 9;                      // image
    const int ir0  = r0 & (HH - 1);                // image row of r0
    const int mb   = (n << 15) + lane;             // mask base for this image

    // ---- 6 mask rows (ir0-1 .. ir0+4), replicate-clamped; dense byte loads
#define IRJ(j) (min(max(ir0 - 1 + (j), 0), HH - 1))
    const u32 m0 = mask[mb + (IRJ(0) << 6)];
    const u32 m1 = mask[mb + (IRJ(1) << 6)];
    const u32 m2 = mask[mb + (IRJ(2) << 6)];
    const u32 m3 = mask[mb + (IRJ(3) << 6)];
    const u32 m4 = mask[mb + (IRJ(4) << 6)];
    const u32 m5 = mask[mb + (IRJ(5) << 6)];
#undef IRJ

    // ---- x loads: 8 dense float4 (2 per row)
    const float* xp = x + r0 * WW + (lane << 3);
    const float4 x0a = *(const float4*)(xp);
    const float4 x0b = *(const float4*)(xp + 4);
    const float4 x1a = *(const float4*)(xp + WW);
    const float4 x1b = *(const float4*)(xp + WW + 4);
    const float4 x2a = *(const float4*)(xp + 2 * WW);
    const float4 x2b = *(const float4*)(xp + 2 * WW + 4);
    const float4 x3a = *(const float4*)(xp + 3 * WW);
    const float4 x3b = *(const float4*)(xp + 3 * WW + 4);

    // ---- packed vertical OR/AND: byte j = output row j
    const u32 M  = m1 | (m2 << 8) | (m3 << 16) | (m4 << 24);  // center masks
    const u32 VO = (m0 | m1 | m2)         | ((m1 | m2 | m3) << 8)
                 | ((m2 | m3 | m4) << 16) | ((m3 | m4 | m5) << 24);
    const u32 VA = (m0 & m1 & m2)         | ((m1 & m2 & m3) << 8)
                 | ((m2 & m3 & m4) << 16) | ((m3 & m4 & m5) << 24);

    // ---- cross-lane neighbor bits (lane edge == image edge: replicate)
    const int iL = (lane + 63) & 63, iR = (lane + 1) & 63;
    const u32 VOLs = __shfl(VO, iL), VALs = __shfl(VA, iL);
    const u32 VORs = __shfl(VO, iR), VARs = __shfl(VA, iR);
    const u32 lbO = (lane == 0)  ? (VO & 0x01010101u) : ((VOLs >> 7) & 0x01010101u);
    const u32 lbA = (lane == 0)  ? (VA & 0x01010101u) : ((VALs >> 7) & 0x01010101u);
    const u32 rbO = (lane == 63) ? (VO & 0x80808080u) : ((VORs & 0x01010101u) << 7);
    const u32 rbA = (lane == 63) ? (VA & 0x80808080u) : ((VARs & 0x01010101u) << 7);

    // ---- horizontal 3-window, byte-wise (mask off cross-byte shift leaks)
    const u32 HO = VO | (((VO << 1) & 0xFEFEFEFEu) | lbO)
                      | (((VO >> 1) & 0x7F7F7F7Fu) | rbO);
    const u32 HA = VA & (((VA << 1) & 0xFEFEFEFEu) | lbA)
                      & (((VA >> 1) & 0x7F7F7F7Fu) | rbA);
    const u32 BD = HO ^ HA;        // border bit (8i+k) = row i, col 8*lane+k

    // ---- per-pixel: max(m?-x:x, 0) + ln(1+e^{-|x|}); weight 2 on border
    float acc = 0.0f;
#define PX(xf, bi) { \
        const float ls = fmaxf(((M >> (bi)) & 1u) ? -(xf) : (xf), 0.0f) \
                       + __logf(1.0f + __expf(-fabsf(xf))); \
        acc = fmaf(ls, ((BD >> (bi)) & 1u) ? 2.0f : 1.0f, acc); }
    PX(x0a.x,  0) PX(x0a.y,  1) PX(x0a.z,  2) PX(x0a.w,  3)
    PX(x0b.x,  4) PX(x0b.y,  5) PX(x0b.z,  6) PX(x0b.w,  7)
    PX(x1a.x,  8) PX(x1a.y,  9) PX(x1a.z, 10) PX(x1a.w, 11)
    PX(x1b.x, 12) PX(x1b.y, 13) PX(x1b.z, 14) PX(x1b.w, 15)
    PX(x2a.x, 16) PX(x2a.y, 17) PX(x2a.z, 18) PX(x2a.w, 19)
    PX(x2b.x, 20) PX(x2b.y, 21) PX(x2b.z, 22) PX(x2b.w, 23)
    PX(x3a.x, 24) PX(x3a.y, 25) PX(x3a.z, 26) PX(x3a.w, 27)
    PX(x3b.x, 28) PX(x3b.y, 29) PX(x3b.z, 30) PX(x3b.w, 31)
#undef PX

    // ---- wave reduce + 4-wave LDS reduce + one atomic per block
    #pragma unroll
    for (int off = 32; off > 0; off >>= 1)
        acc += __shfl_down(acc, off);
    if (lane == 0) wsum[tid >> 6] = acc;
    __syncthreads();
    if (tid == 0) {
        const float t = wsum[0] + wsum[1] + wsum[2] + wsum[3];
        atomicAdd(out, t * INV_TOTAL);
    }
}

// ---------------- Fallback (R8 fused, y read 3x) — if ws too small ---------
__global__ __launch_bounds__(256, 8) void border_loss_fused(
    const float* __restrict__ x, const int* __restrict__ y,
    float* __restrict__ out)
{
    __shared__ float wsum[4];
    const int tid  = threadIdx.x;
    const int idx  = blockIdx.x * 256 + tid;
    const int lane = tid & 63;
    const int r    = (idx >> 6) & (HH - 1);
    const int n    = idx >> 15;
    const int rowb = n * (HH * WW) + r * WW;
    const int pC = rowb + (lane << 3);
    const int pT = pC + ((r > 0)      ? -WW : 0);
    const int pB = pC + ((r < HH - 1) ?  WW : 0);

    const int4   t0 = *(const int4*)(y + pT);
    const int4   t1 = *(const int4*)(y + pT + 4);
    const int4   c0 = *(const int4*)(y + pC);
    const int4   c1 = *(const int4*)(y + pC + 4);
    const int4   b0 = *(const int4*)(y + pB);
    const int4   b1 = *(const int4*)(y + pB + 4);
    const float4 xa = *(const float4*)(x + pC);
    const float4 xb = *(const float4*)(x + pC + 4);

    const int vo0 = t0.x | c0.x | b0.x;  const int va0 = t0.x & c0.x & b0.x;
    const int vo1 = t0.y | c0.y | b0.y;  const int va1 = t0.y & c0.y & b0.y;
    const int vo2 = t0.z | c0.z | b0.z;  const int va2 = t0.z & c0.z & b0.z;
    const int vo3 = t0.w | c0.w | b0.w;  const int va3 = t0.w & c0.w & b0.w;
    const int vo4 = t1.x | c1.x | b1.x;  const int va4 = t1.x & c1.x & b1.x;
    const int vo5 = t1.y | c1.y | b1.y;  const int va5 = t1.y & c1.y & b1.y;
    const int vo6 = t1.z | c1.z | b1.z;  const int va6 = t1.z & c1.z & b1.z;
    const int vo7 = t1.w | c1.w | b1.w;  const int va7 = t1.w & c1.w & b1.w;

    const int iL = (lane + 63) & 63, iR = (lane + 1) & 63;
    const int voL = (lane == 0)  ? vo0 : __shfl(vo7, iL);
    const int vaL = (lane == 0)  ? va0 : __shfl(va7, iL);
    const int voR = (lane == 63) ? vo7 : __shfl(vo0, iR);
    const int vaR = (lane == 63) ? va7 : __shfl(va0, iR);

    const int ho0 = voL | vo0 | vo1;  const int ha0 = vaL & va0 & va1;
    const int ho1 = vo0 | vo1 | vo2;  const int ha1 = va0 & va1 & va2;
    const int ho2 = vo1 | vo2 | vo3;  const int ha2 = va1 & va2 & va3;
    const int ho3 = vo2 | vo3 | vo4;  const int ha3 = va2 & va3 & va4;
    const int ho4 = vo3 | vo4 | vo5;  const int ha4 = va3 & va4 & va5;
    const int ho5 = vo4 | vo5 | vo6;  const int ha5 = va4 & va5 & va6;
    const int ho6 = vo5 | vo6 | vo7;  const int ha6 = va5 & va6 & va7;
    const int ho7 = vo6 | vo7 | voR;  const int ha7 = va6 & va7 & vaR;

    float acc = 0.0f;
#define PX(xf, m, ho, ha) { \
        const float ls = fmaxf((m) ? -(xf) : (xf), 0.0f) \
                       + __logf(1.0f + __expf(-fabsf(xf))); \
        acc = fmaf(ls, (float)(1 + ((ho) ^ (ha))), acc); }
    PX(xa.x, c0.x, ho0, ha0) PX(xa.y, c0.y, ho1, ha1)
    PX(xa.z, c0.z, ho2, ha2) PX(xa.w, c0.w, ho3, ha3)
    PX(xb.x, c1.x, ho4, ha4) PX(xb.y, c1.y, ho5, ha5)
    PX(xb.z, c1.z, ho6, ha6) PX(xb.w, c1.w, ho7, ha7)
#undef PX

    #pragma unroll
    for (int off = 32; off > 0; off >>= 1)
        acc += __shfl_down(acc, off);
    if (lane == 0) wsum[tid >> 6] = acc;
    __syncthreads();
    if (tid == 0) {
        const float t = wsum[0] + wsum[1] + wsum[2] + wsum[3];
        atomicAdd(out, t * INV_TOTAL);
    }
}

__global__ void border_loss_zero(float* out) { out[0] = 0.0f; }

extern "C" void kernel_launch(void* const* d_in, const int* in_sizes, int n_in,
                              void* d_out, int out_size, void* d_ws, size_t ws_size,
                              hipStream_t stream)
{
    const float* x = (const float*)d_in[0];
    const int*   y = (const int*)d_in[1];
    float* out = (float*)d_out;

    if (ws_size >= (size_t)MASK_BYTES) {
        // Two-pass: y -> bitmask (zeroes out), then x + bitmask -> loss sum.
        u8* mask = (u8*)d_ws;
        border_mask_gen<<<NBLK_A, 256, 0, stream>>>(y, mask, out);
        border_loss_bits<<<NBLK_B, 256, 0, stream>>>(x, mask, out);
    } else {
        border_loss_zero<<<1, 1, 0, stream>>>(out);
        border_loss_fused<<<NBLK_A, 256, 0, stream>>>(x, y, out);
    }
}